// Round 15
// baseline (168.128 us; speedup 1.0000x reference)
//
#include <hip/hip_runtime.h>

#define NB    256   // neighbors
#define DIN   64
#define LATD  128
#define ECD   32

typedef __attribute__((ext_vector_type(8))) __bf16 bf16x8;
typedef __attribute__((ext_vector_type(4))) float f32x4;

#define XS_STRIDE 72   // row stride for WcT/WfT in d_ws (bf16 elems)
#define EC_STRIDE 40   // ec tile row stride (shorts)
#define WA_STRIDE 40

// d_ws layout (unsigned short elements)
#define WS_WC 0                     // WcT  [32][72]
#define WS_WF (32 * 72)             // WfT  [128][72]
#define WS_WA (32 * 72 + 128 * 72)  // WaTm [128][40]  (Wa rows 32..63, transposed, *log2e)

#define MFMA(a, b, c) __builtin_amdgcn_mfma_f32_16x16x32_bf16((a), (b), (c), 0, 0, 0)

__device__ __forceinline__ unsigned short f2bf(float f) {
    unsigned u = __builtin_bit_cast(unsigned, f);
    u += 0x7fffu + ((u >> 16) & 1u);   // round-to-nearest-even
    return (unsigned short)(u >> 16);
}

// Packed f32->bf16 RNE (gfx950; no builtin). Plain VALU -> no TRANS hazard.
__device__ __forceinline__ unsigned cvt2(float lo, float hi) {
    unsigned r;
    asm("v_cvt_pk_bf16_f32 %0, %1, %2" : "=v"(r) : "v"(lo), "v"(hi));
    return r;
}

// Single-instruction exp2. r4 LESSON: raw asm v_exp_f32 has an invisible
// TRANS hazard (absmax 1.5); the builtin adds compiler-managed hazards.
#if __has_builtin(__builtin_amdgcn_exp2f)
__device__ __forceinline__ float fexp2(float x) {
    return __builtin_amdgcn_exp2f(x);
}
#else
__device__ __forceinline__ float fexp2(float x) {
    float r;
    asm("v_exp_f32 %0, %1\n\ts_nop 1" : "=v"(r) : "v"(x));
    return r;
}
#endif

__device__ __forceinline__ bf16x8 pack8(float4 a, float4 b) {
    union { unsigned u[4]; bf16x8 v; } r;
    r.u[0] = cvt2(a.x, a.y);
    r.u[1] = cvt2(a.z, a.w);
    r.u[2] = cvt2(b.x, b.y);
    r.u[3] = cvt2(b.z, b.w);
    return r.v;
}

// HBM->LDS direct (width 16): zero VGPR staging cost. LDS dest is
// wave-uniform base + lane*16; global src is per-lane (pre-swizzled).
__device__ __forceinline__ void gload_lds16(const void* g, void* l) {
    __builtin_amdgcn_global_load_lds(
        (const __attribute__((address_space(1))) unsigned int*)g,
        (__attribute__((address_space(3))) unsigned int*)l, 16, 0, 0);
}

// Pre-transpose weights into bf16 B-fragment-friendly [n][k] layouts in d_ws.
// Wa rows 32..63 are pre-scaled by log2e so the kernel can use exp2 directly.
__global__ __launch_bounds__(256) void prep_kernel(
    const float* __restrict__ Wc, const float* __restrict__ Wf,
    const float* __restrict__ Wa, unsigned short* __restrict__ ws)
{
    int t = blockIdx.x * blockDim.x + threadIdx.x;
    int stride = gridDim.x * blockDim.x;
    for (int i = t; i < 32 * 64; i += stride) {
        int n = i >> 6, k = i & 63;
        ws[WS_WC + n * XS_STRIDE + k] = f2bf(Wc[k * ECD + n]);
    }
    for (int i = t; i < 128 * 64; i += stride) {
        int n = i >> 6, k = i & 63;
        ws[WS_WF + n * XS_STRIDE + k] = f2bf(Wf[k * LATD + n]);
    }
    for (int i = t; i < 128 * 32; i += stride) {
        int n = i >> 5, k = i & 31;
        ws[WS_WA + n * WA_STRIDE + k] = f2bf(Wa[(ECD + k) * LATD + n] * 1.44269504f);
    }
}

// r14 post-mortem: weight source triple-falsified (L2==LDS==regs); r13/r14
// streaming plateau at ~40us with only 8 waves/CU. UNTESTED CELL: good
// access pattern x high TLP — all prior occupancy tests (r1/r3/r5/r9) used
// the scattered gather. THIS REV: 1024 blocks x 1 element, streaming
// single-buffered gload_lds ingestion (r13-proven, bit-exact), 16 waves/CU
// (launch_bounds(256,4): VGPR<=128, LDS 27.1KB -> 4 blocks/CU resident).
// Weights via rolling L2 prefetch (r5-proven; wstage/registers both blow
// the 4-block budgets). TLP now covers the residual chains (weight-load
// latency, LDS round-trips, exp chains) that 8 waves/CU could not.
// Key algebra (verified): self_rep/mean_rep/ba constant along n -> cancel
// in softmax(axis=n); att = softmax_n(enc_comm @ Wa[32:64]); local_data /
// Wa[0:32] / Wa[64:96] / ba never touch the output.
__global__ __launch_bounds__(256, 4) void arm_main(
    const float* __restrict__ xg,   // neighbor [B][256][64]
    const float* __restrict__ bcv,  // bc [32]
    const float* __restrict__ bfv,  // bf [128]
    const float* __restrict__ wl,   // Wl [128][128]
    const float* __restrict__ blv,  // bl [128]
    const unsigned short* __restrict__ ws,
    float* __restrict__ out)        // [B][128]
{
    __shared__ float xstage[4][1024];                  // 16384 B [wave][16 rows x 256B]
    __shared__ unsigned short ecst[4][16 * EC_STRIDE]; // 5120 B per-wave ec tile
    __shared__ float aggnum[4][LATD];                  // 2048 B [wave][col]
    __shared__ float aggden[4][LATD];                  // 2048 B
    __shared__ float aggfull[LATD];                    // 512 B
    __shared__ float wlpart[2][LATD];                  // 1024 B
    // total 27136 B -> 4 blocks/CU (LDS 108KB/160KB; VGPR cap 128)

    const int b    = blockIdx.x;          // gridDim.x == 1024, 1 elem/block
    const int tid  = threadIdx.x;
    const int lane = tid & 63;
    const int w    = tid >> 6;   // wave id, owns rows 64w..64w+63
    const int l15  = lane & 15;
    const int q    = lane >> 4;

    // ---- element-invariant: Wc frags + bc (L2, registers; 18 VGPR) ----
    bf16x8 wfrag[2][2];
    #pragma unroll
    for (int ks = 0; ks < 2; ++ks)
        #pragma unroll
        for (int nb = 0; nb < 2; ++nb)
            wfrag[ks][nb] = *reinterpret_cast<const bf16x8*>(
                &ws[WS_WC + (nb * 16 + l15) * XS_STRIDE + ks * 32 + q * 8]);
    float bc0 = bcv[l15], bc1 = bcv[16 + l15];

    // ---- staging: 4 tiles of 16 rows x 256B, single-buffered, issue-early.
    // Linear LDS off Li = i*1024 + lane*16; row = i*4 + q (tile-local).
    // Global src = Li ^ ((row&7)<<4)  (involution; verified bit-exact r12/r13).
    const float* xw = xg + (size_t)b * NB * DIN + w * 64 * DIN;

#define STAGE(s_)                                                             \
    {                                                                         \
        const char* tb = (const char*)(xw + (s_) * 1024);                     \
        float* lb = &xstage[w][0];                                            \
        _Pragma("unroll")                                                     \
        for (int i = 0; i < 4; ++i) {                                         \
            unsigned off = (unsigned)(i * 1024 + lane * 16);                  \
            unsigned r7  = (unsigned)((i * 4 + q) & 7);                       \
            gload_lds16(tb + (off ^ (r7 << 4)), lb + i * 256);                \
        }                                                                     \
    }

    STAGE(0);

    float num[8] = {0.f, 0.f, 0.f, 0.f, 0.f, 0.f, 0.f, 0.f};
    float den[8] = {0.f, 0.f, 0.f, 0.f, 0.f, 0.f, 0.f, 0.f};

    // frag read offsets (swizzled): o0 = (l15*256 + q*32) ^ ((l15&7)<<4);
    // +16/+128/+144 toggles live in untouched bits -> XOR composition exact.
    const unsigned o0 = ((unsigned)(l15 * 256 + q * 32)) ^ ((unsigned)(l15 & 7) << 4);

    const unsigned short* wfb = ws + WS_WF;
    const unsigned short* wab = ws + WS_WA;

    #pragma unroll 1
    for (int s = 0; s < 4; ++s) {
        // (1) tile s resident (drains staging + any older weight prefetch)
        asm volatile("s_waitcnt vmcnt(0)" ::: "memory");

        // (2) fragment reads (4 x ds_read_b128, conflict-free via swizzle)
        const char* xb = (const char*)&xstage[w][0];
        float4 r0 = *reinterpret_cast<const float4*>(xb + o0);
        float4 r1 = *reinterpret_cast<const float4*>(xb + (o0 ^ 16));
        float4 r2 = *reinterpret_cast<const float4*>(xb + (o0 ^ 128));
        float4 r3 = *reinterpret_cast<const float4*>(xb + (o0 ^ 144));

        // (3) reads retired -> safe to overwrite buffer with tile s+1;
        // issued BEFORE compute so ~1 compute phase covers its latency.
        asm volatile("s_waitcnt lgkmcnt(0)" ::: "memory");
        if (s < 3) { STAGE(s + 1); }

        bf16x8 xf0 = pack8(r0, r1);
        bf16x8 xf1 = pack8(r2, r3);

        // (4) enc_comm tile: relu(X*Wc + bc) -> ec tile (wave-private LDS;
        // same-wave DS ordering, no barrier). Bias folded into acc init.
        f32x4 a0 = {bc0, bc0, bc0, bc0};
        f32x4 a1 = {bc1, bc1, bc1, bc1};
        a0 = MFMA(xf0, wfrag[0][0], a0); a0 = MFMA(xf1, wfrag[1][0], a0);
        a1 = MFMA(xf0, wfrag[0][1], a1); a1 = MFMA(xf1, wfrag[1][1], a1);
        #pragma unroll
        for (int r = 0; r < 4; ++r) {
            int row = q * 4 + r;   // C/D: row = quad*4 + reg (tile-local)
            unsigned pk = cvt2(fmaxf(a0[r], 0.f), fmaxf(a1[r], 0.f));
            ecst[w][row * EC_STRIDE + l15]      = (unsigned short)pk;
            ecst[w][row * EC_STRIDE + 16 + l15] = (unsigned short)(pk >> 16);
        }
        bf16x8 ecf = *reinterpret_cast<const bf16x8*>(&ecst[w][l15 * EC_STRIDE + q * 8]);

        // (5) all 8 g for this tile; weights via rolling L2 prefetch
        // (r5-proven: g+1's loads issued before g's math, latency hidden).
        bf16x8 wf0 = *reinterpret_cast<const bf16x8*>(&wfb[l15 * XS_STRIDE + q * 8]);
        bf16x8 wf1 = *reinterpret_cast<const bf16x8*>(&wfb[l15 * XS_STRIDE + 32 + q * 8]);
        bf16x8 wag = *reinterpret_cast<const bf16x8*>(&wab[l15 * WA_STRIDE + q * 8]);
        float  bfl = bfv[l15];

        #pragma unroll
        for (int g = 0; g < 8; ++g) {
            bf16x8 nwf0, nwf1, nwag;
            float  nbfl = 0.f;
            if (g < 7) {
                int rn = (g + 1) * 16 + l15;
                nwf0 = *reinterpret_cast<const bf16x8*>(&wfb[rn * XS_STRIDE + q * 8]);
                nwf1 = *reinterpret_cast<const bf16x8*>(&wfb[rn * XS_STRIDE + 32 + q * 8]);
                nwag = *reinterpret_cast<const bf16x8*>(&wab[rn * WA_STRIDE + q * 8]);
                nbfl = bfv[rn];
            }

            f32x4 z = {bfl, bfl, bfl, bfl};   // bf bias in acc init
            z = MFMA(xf0, wf0, z);
            f32x4 ef = MFMA(xf1, wf1, z);
            f32x4 zz = {0.f, 0.f, 0.f, 0.f};  // ba cancels
            f32x4 lg = MFMA(ecf, wag, zz);
            #pragma unroll
            for (int r = 0; r < 4; ++r) {
                float ev = fmaxf(ef[r], 0.f);
                float p  = fexp2(lg[r]);      // Wa pre-scaled by log2e
                num[g] = fmaf(p, ev, num[g]);
                den[g] += p;
            }

            if (g < 7) { wf0 = nwf0; wf1 = nwf1; wag = nwag; bfl = nbfl; }
        }
    }
#undef STAGE

    // ---- reduce across lanes, store wave partials ----
    #pragma unroll
    for (int g = 0; g < 8; ++g) {
        float n2 = num[g], d2 = den[g];
        n2 += __shfl_xor(n2, 16, 64); n2 += __shfl_xor(n2, 32, 64);
        d2 += __shfl_xor(d2, 16, 64); d2 += __shfl_xor(d2, 32, 64);
        if (lane < 16) {
            aggnum[w][g * 16 + lane] = n2;
            aggden[w][g * 16 + lane] = d2;
        }
    }
    __syncthreads();

    // ---- combine wave partials: aggregated[k] = sum(num)/sum(den) ----
    if (tid < 128) {
        float n2 = aggnum[0][tid] + aggnum[1][tid] + aggnum[2][tid] + aggnum[3][tid];
        float d2 = aggden[0][tid] + aggden[1][tid] + aggden[2][tid] + aggden[3][tid];
        aggfull[tid] = n2 / d2;
    }
    __syncthreads();

    // ---- out = relu(agg @ Wl + bl), k-range split over thread halves ----
    {
        int c = tid & 127, h = tid >> 7;
        float acc = 0.f;
        #pragma unroll 16
        for (int k = h * 64; k < h * 64 + 64; ++k)
            acc = fmaf(aggfull[k], wl[k * LATD + c], acc);
        wlpart[h][c] = acc;
    }
    __syncthreads();
    if (tid < 128)
        out[(size_t)b * LATD + tid] =
            fmaxf(wlpart[0][tid] + wlpart[1][tid] + blv[tid], 0.f);
}

extern "C" void kernel_launch(void* const* d_in, const int* in_sizes, int n_in,
                              void* d_out, int out_size, void* d_ws, size_t ws_size,
                              hipStream_t stream)
{
    const float* xg  = (const float*)d_in[1];
    const float* wc  = (const float*)d_in[2];
    const float* bc_ = (const float*)d_in[3];
    const float* wf  = (const float*)d_in[4];
    const float* bf_ = (const float*)d_in[5];
    const float* wa  = (const float*)d_in[6];
    const float* wl  = (const float*)d_in[8];
    const float* bl_ = (const float*)d_in[9];
    unsigned short* wsp = (unsigned short*)d_ws;   // needs 33,280 B of ws
    float* out = (float*)d_out;

    prep_kernel<<<8, 256, 0, stream>>>(wc, wf, wa, wsp);
    arm_main<<<1024, 256, 0, stream>>>(xg, bc_, bf_, wl, bl_, wsp, out);
}

// Round 16
// 132.083 us; speedup vs baseline: 1.2729x; 1.2729x over previous
//
#include <hip/hip_runtime.h>

#define NB    256   // neighbors
#define DIN   64
#define LATD  128
#define ECD   32

typedef __attribute__((ext_vector_type(8))) __bf16 bf16x8;
typedef __attribute__((ext_vector_type(4))) float f32x4;

#define XS_STRIDE 72   // row stride for WcT/WfT in d_ws (bf16 elems)
#define EC_STRIDE 40   // ec tile row stride (shorts)
#define WA_STRIDE 40

// d_ws layout (unsigned short elements)
#define WS_WC 0                     // WcT  [32][72]
#define WS_WF (32 * 72)             // WfT  [128][72]
#define WS_WA (32 * 72 + 128 * 72)  // WaTm [128][40]  (Wa rows 32..63, transposed, *log2e)

#define MFMA(a, b, c) __builtin_amdgcn_mfma_f32_16x16x32_bf16((a), (b), (c), 0, 0, 0)

__device__ __forceinline__ unsigned short f2bf(float f) {
    unsigned u = __builtin_bit_cast(unsigned, f);
    u += 0x7fffu + ((u >> 16) & 1u);   // round-to-nearest-even
    return (unsigned short)(u >> 16);
}

// Packed f32->bf16 RNE (gfx950; no builtin). Plain VALU -> no TRANS hazard.
__device__ __forceinline__ unsigned cvt2(float lo, float hi) {
    unsigned r;
    asm("v_cvt_pk_bf16_f32 %0, %1, %2" : "=v"(r) : "v"(lo), "v"(hi));
    return r;
}

// Single-instruction exp2. r4 LESSON: raw asm v_exp_f32 has an invisible
// TRANS hazard (absmax 1.5); the builtin adds compiler-managed hazards.
#if __has_builtin(__builtin_amdgcn_exp2f)
__device__ __forceinline__ float fexp2(float x) {
    return __builtin_amdgcn_exp2f(x);
}
#else
__device__ __forceinline__ float fexp2(float x) {
    float r;
    asm("v_exp_f32 %0, %1\n\ts_nop 1" : "=v"(r) : "v"(x));
    return r;
}
#endif

__device__ __forceinline__ bf16x8 pack8(float4 a, float4 b) {
    union { unsigned u[4]; bf16x8 v; } r;
    r.u[0] = cvt2(a.x, a.y);
    r.u[1] = cvt2(a.z, a.w);
    r.u[2] = cvt2(b.x, b.y);
    r.u[3] = cvt2(b.z, b.w);
    return r.v;
}

// HBM->LDS direct (width 16): zero VGPR staging cost. LDS dest is
// wave-uniform base + lane*16; global src is per-lane (pre-swizzled).
__device__ __forceinline__ void gload_lds16(const void* g, void* l) {
    __builtin_amdgcn_global_load_lds(
        (const __attribute__((address_space(1))) unsigned int*)g,
        (__attribute__((address_space(3))) unsigned int*)l, 16, 0, 0);
}

// Pre-transpose weights into bf16 B-fragment-friendly [n][k] layouts in d_ws.
// Wa rows 32..63 are pre-scaled by log2e so the kernel can use exp2 directly.
__global__ __launch_bounds__(256) void prep_kernel(
    const float* __restrict__ Wc, const float* __restrict__ Wf,
    const float* __restrict__ Wa, unsigned short* __restrict__ ws)
{
    int t = blockIdx.x * blockDim.x + threadIdx.x;
    int stride = gridDim.x * blockDim.x;
    for (int i = t; i < 32 * 64; i += stride) {
        int n = i >> 6, k = i & 63;
        ws[WS_WC + n * XS_STRIDE + k] = f2bf(Wc[k * ECD + n]);
    }
    for (int i = t; i < 128 * 64; i += stride) {
        int n = i >> 6, k = i & 63;
        ws[WS_WF + n * XS_STRIDE + k] = f2bf(Wf[k * LATD + n]);
    }
    for (int i = t; i < 128 * 32; i += stride) {
        int n = i >> 5, k = i & 31;
        ws[WS_WA + n * WA_STRIDE + k] = f2bf(Wa[(ECD + k) * LATD + n] * 1.44269504f);
    }
}

// r15 post-mortem: the high-TLP x streaming test was INVALIDATED — the
// allocator over-restricted to 64 VGPR (chasing the 8-wave/SIMD occupancy
// step, beyond the launch_bounds contract) and spilled (WRITE 41MB,
// FETCH 95MB). THIS REV re-runs the same cell de-risked:
// __launch_bounds__(256,3) -> ~170-VGPR budget (working set ~130 fits with
// margin -> no spill possible), LDS 27.1KB -> 3 blocks/CU = 12 waves/CU
// (1.5x r13/r14's 8). Everything else identical to r15 (1024 blocks x
// 1 element, streaming single-buffered gload_lds, rolling L2 weight
// prefetch — all previously verified bit-exact).
// Canaries: VGPR in [120,168] and WRITE < 1MB, else conclusions void.
// Key algebra (verified): self_rep/mean_rep/ba constant along n -> cancel
// in softmax(axis=n); att = softmax_n(enc_comm @ Wa[32:64]); local_data /
// Wa[0:32] / Wa[64:96] / ba never touch the output.
__global__ __launch_bounds__(256, 3) void arm_main(
    const float* __restrict__ xg,   // neighbor [B][256][64]
    const float* __restrict__ bcv,  // bc [32]
    const float* __restrict__ bfv,  // bf [128]
    const float* __restrict__ wl,   // Wl [128][128]
    const float* __restrict__ blv,  // bl [128]
    const unsigned short* __restrict__ ws,
    float* __restrict__ out)        // [B][128]
{
    __shared__ float xstage[4][1024];                  // 16384 B [wave][16 rows x 256B]
    __shared__ unsigned short ecst[4][16 * EC_STRIDE]; // 5120 B per-wave ec tile
    __shared__ float aggnum[4][LATD];                  // 2048 B [wave][col]
    __shared__ float aggden[4][LATD];                  // 2048 B
    __shared__ float aggfull[LATD];                    // 512 B
    __shared__ float wlpart[2][LATD];                  // 1024 B
    // total 27136 B -> LDS allows 5 blocks/CU; VGPR (~170) binds at 3

    const int b    = blockIdx.x;          // gridDim.x == 1024, 1 elem/block
    const int tid  = threadIdx.x;
    const int lane = tid & 63;
    const int w    = tid >> 6;   // wave id, owns rows 64w..64w+63
    const int l15  = lane & 15;
    const int q    = lane >> 4;

    // ---- element-invariant: Wc frags + bc (L2, registers; 18 VGPR) ----
    bf16x8 wfrag[2][2];
    #pragma unroll
    for (int ks = 0; ks < 2; ++ks)
        #pragma unroll
        for (int nb = 0; nb < 2; ++nb)
            wfrag[ks][nb] = *reinterpret_cast<const bf16x8*>(
                &ws[WS_WC + (nb * 16 + l15) * XS_STRIDE + ks * 32 + q * 8]);
    float bc0 = bcv[l15], bc1 = bcv[16 + l15];

    // ---- staging: 4 tiles of 16 rows x 256B, single-buffered, issue-early.
    // Linear LDS off Li = i*1024 + lane*16; row = i*4 + q (tile-local).
    // Global src = Li ^ ((row&7)<<4)  (involution; verified bit-exact r12/r13).
    const float* xw = xg + (size_t)b * NB * DIN + w * 64 * DIN;

#define STAGE(s_)                                                             \
    {                                                                         \
        const char* tb = (const char*)(xw + (s_) * 1024);                     \
        float* lb = &xstage[w][0];                                            \
        _Pragma("unroll")                                                     \
        for (int i = 0; i < 4; ++i) {                                         \
            unsigned off = (unsigned)(i * 1024 + lane * 16);                  \
            unsigned r7  = (unsigned)((i * 4 + q) & 7);                       \
            gload_lds16(tb + (off ^ (r7 << 4)), lb + i * 256);                \
        }                                                                     \
    }

    STAGE(0);

    float num[8] = {0.f, 0.f, 0.f, 0.f, 0.f, 0.f, 0.f, 0.f};
    float den[8] = {0.f, 0.f, 0.f, 0.f, 0.f, 0.f, 0.f, 0.f};

    // frag read offsets (swizzled): o0 = (l15*256 + q*32) ^ ((l15&7)<<4);
    // +16/+128/+144 toggles live in untouched bits -> XOR composition exact.
    const unsigned o0 = ((unsigned)(l15 * 256 + q * 32)) ^ ((unsigned)(l15 & 7) << 4);

    const unsigned short* wfb = ws + WS_WF;
    const unsigned short* wab = ws + WS_WA;

    #pragma unroll 1
    for (int s = 0; s < 4; ++s) {
        // (1) tile s resident (drains staging + any older weight prefetch)
        asm volatile("s_waitcnt vmcnt(0)" ::: "memory");

        // (2) fragment reads (4 x ds_read_b128, conflict-free via swizzle)
        const char* xb = (const char*)&xstage[w][0];
        float4 r0 = *reinterpret_cast<const float4*>(xb + o0);
        float4 r1 = *reinterpret_cast<const float4*>(xb + (o0 ^ 16));
        float4 r2 = *reinterpret_cast<const float4*>(xb + (o0 ^ 128));
        float4 r3 = *reinterpret_cast<const float4*>(xb + (o0 ^ 144));

        // (3) reads retired -> safe to overwrite buffer with tile s+1;
        // issued BEFORE compute so ~1 compute phase covers its latency.
        asm volatile("s_waitcnt lgkmcnt(0)" ::: "memory");
        if (s < 3) { STAGE(s + 1); }

        bf16x8 xf0 = pack8(r0, r1);
        bf16x8 xf1 = pack8(r2, r3);

        // (4) enc_comm tile: relu(X*Wc + bc) -> ec tile (wave-private LDS;
        // same-wave DS ordering, no barrier). Bias folded into acc init.
        f32x4 a0 = {bc0, bc0, bc0, bc0};
        f32x4 a1 = {bc1, bc1, bc1, bc1};
        a0 = MFMA(xf0, wfrag[0][0], a0); a0 = MFMA(xf1, wfrag[1][0], a0);
        a1 = MFMA(xf0, wfrag[0][1], a1); a1 = MFMA(xf1, wfrag[1][1], a1);
        #pragma unroll
        for (int r = 0; r < 4; ++r) {
            int row = q * 4 + r;   // C/D: row = quad*4 + reg (tile-local)
            unsigned pk = cvt2(fmaxf(a0[r], 0.f), fmaxf(a1[r], 0.f));
            ecst[w][row * EC_STRIDE + l15]      = (unsigned short)pk;
            ecst[w][row * EC_STRIDE + 16 + l15] = (unsigned short)(pk >> 16);
        }
        bf16x8 ecf = *reinterpret_cast<const bf16x8*>(&ecst[w][l15 * EC_STRIDE + q * 8]);

        // (5) all 8 g for this tile; weights via rolling L2 prefetch
        // (r5-proven: g+1's loads issued before g's math, latency hidden).
        bf16x8 wf0 = *reinterpret_cast<const bf16x8*>(&wfb[l15 * XS_STRIDE + q * 8]);
        bf16x8 wf1 = *reinterpret_cast<const bf16x8*>(&wfb[l15 * XS_STRIDE + 32 + q * 8]);
        bf16x8 wag = *reinterpret_cast<const bf16x8*>(&wab[l15 * WA_STRIDE + q * 8]);
        float  bfl = bfv[l15];

        #pragma unroll
        for (int g = 0; g < 8; ++g) {
            bf16x8 nwf0, nwf1, nwag;
            float  nbfl = 0.f;
            if (g < 7) {
                int rn = (g + 1) * 16 + l15;
                nwf0 = *reinterpret_cast<const bf16x8*>(&wfb[rn * XS_STRIDE + q * 8]);
                nwf1 = *reinterpret_cast<const bf16x8*>(&wfb[rn * XS_STRIDE + 32 + q * 8]);
                nwag = *reinterpret_cast<const bf16x8*>(&wab[rn * WA_STRIDE + q * 8]);
                nbfl = bfv[rn];
            }

            f32x4 z = {bfl, bfl, bfl, bfl};   // bf bias in acc init
            z = MFMA(xf0, wf0, z);
            f32x4 ef = MFMA(xf1, wf1, z);
            f32x4 zz = {0.f, 0.f, 0.f, 0.f};  // ba cancels
            f32x4 lg = MFMA(ecf, wag, zz);
            #pragma unroll
            for (int r = 0; r < 4; ++r) {
                float ev = fmaxf(ef[r], 0.f);
                float p  = fexp2(lg[r]);      // Wa pre-scaled by log2e
                num[g] = fmaf(p, ev, num[g]);
                den[g] += p;
            }

            if (g < 7) { wf0 = nwf0; wf1 = nwf1; wag = nwag; bfl = nbfl; }
        }
    }
#undef STAGE

    // ---- reduce across lanes, store wave partials ----
    #pragma unroll
    for (int g = 0; g < 8; ++g) {
        float n2 = num[g], d2 = den[g];
        n2 += __shfl_xor(n2, 16, 64); n2 += __shfl_xor(n2, 32, 64);
        d2 += __shfl_xor(d2, 16, 64); d2 += __shfl_xor(d2, 32, 64);
        if (lane < 16) {
            aggnum[w][g * 16 + lane] = n2;
            aggden[w][g * 16 + lane] = d2;
        }
    }
    __syncthreads();

    // ---- combine wave partials: aggregated[k] = sum(num)/sum(den) ----
    if (tid < 128) {
        float n2 = aggnum[0][tid] + aggnum[1][tid] + aggnum[2][tid] + aggnum[3][tid];
        float d2 = aggden[0][tid] + aggden[1][tid] + aggden[2][tid] + aggden[3][tid];
        aggfull[tid] = n2 / d2;
    }
    __syncthreads();

    // ---- out = relu(agg @ Wl + bl), k-range split over thread halves ----
    {
        int c = tid & 127, h = tid >> 7;
        float acc = 0.f;
        #pragma unroll 16
        for (int k = h * 64; k < h * 64 + 64; ++k)
            acc = fmaf(aggfull[k], wl[k * LATD + c], acc);
        wlpart[h][c] = acc;
    }
    __syncthreads();
    if (tid < 128)
        out[(size_t)b * LATD + tid] =
            fmaxf(wlpart[0][tid] + wlpart[1][tid] + blv[tid], 0.f);
}

extern "C" void kernel_launch(void* const* d_in, const int* in_sizes, int n_in,
                              void* d_out, int out_size, void* d_ws, size_t ws_size,
                              hipStream_t stream)
{
    const float* xg  = (const float*)d_in[1];
    const float* wc  = (const float*)d_in[2];
    const float* bc_ = (const float*)d_in[3];
    const float* wf  = (const float*)d_in[4];
    const float* bf_ = (const float*)d_in[5];
    const float* wa  = (const float*)d_in[6];
    const float* wl  = (const float*)d_in[8];
    const float* bl_ = (const float*)d_in[9];
    unsigned short* wsp = (unsigned short*)d_ws;   // needs 33,280 B of ws
    float* out = (float*)d_out;

    prep_kernel<<<8, 256, 0, stream>>>(wc, wf, wa, wsp);
    arm_main<<<1024, 256, 0, stream>>>(xg, bc_, bf_, wl, bl_, wsp, out);
}

// Round 17
// 122.767 us; speedup vs baseline: 1.3695x; 1.0759x over previous
//
#include <hip/hip_runtime.h>

#define NB    256   // neighbors
#define DIN   64
#define LATD  128
#define ECD   32

typedef __attribute__((ext_vector_type(8))) __bf16 bf16x8;
typedef __attribute__((ext_vector_type(4))) float f32x4;

#define XS_STRIDE 72   // row stride for WcT/WfT in d_ws (bf16 elems)
#define EC_STRIDE 40   // ec tile row stride (shorts)
#define WA_STRIDE 40

// d_ws layout (unsigned short elements)
#define WS_WC 0                     // WcT  [32][72]
#define WS_WF (32 * 72)             // WfT  [128][72]
#define WS_WA (32 * 72 + 128 * 72)  // WaTm [128][40]  (Wa rows 32..63, transposed, *log2e)

#define MFMA(a, b, c) __builtin_amdgcn_mfma_f32_16x16x32_bf16((a), (b), (c), 0, 0, 0)

__device__ __forceinline__ unsigned short f2bf(float f) {
    unsigned u = __builtin_bit_cast(unsigned, f);
    u += 0x7fffu + ((u >> 16) & 1u);   // round-to-nearest-even
    return (unsigned short)(u >> 16);
}

// Packed f32->bf16 RNE (gfx950; no builtin). Plain VALU -> no TRANS hazard.
__device__ __forceinline__ unsigned cvt2(float lo, float hi) {
    unsigned r;
    asm("v_cvt_pk_bf16_f32 %0, %1, %2" : "=v"(r) : "v"(lo), "v"(hi));
    return r;
}

// Single-instruction exp2. r4 LESSON: raw asm v_exp_f32 has an invisible
// TRANS hazard (absmax 1.5); the builtin adds compiler-managed hazards.
#if __has_builtin(__builtin_amdgcn_exp2f)
__device__ __forceinline__ float fexp2(float x) {
    return __builtin_amdgcn_exp2f(x);
}
#else
__device__ __forceinline__ float fexp2(float x) {
    float r;
    asm("v_exp_f32 %0, %1\n\ts_nop 1" : "=v"(r) : "v"(x));
    return r;
}
#endif

__device__ __forceinline__ bf16x8 pack8(float4 a, float4 b) {
    union { unsigned u[4]; bf16x8 v; } r;
    r.u[0] = cvt2(a.x, a.y);
    r.u[1] = cvt2(a.z, a.w);
    r.u[2] = cvt2(b.x, b.y);
    r.u[3] = cvt2(b.z, b.w);
    return r.v;
}

// HBM->LDS direct (width 16): zero VGPR staging cost. LDS dest is
// wave-uniform base + lane*16; global src is per-lane (pre-swizzled).
__device__ __forceinline__ void gload_lds16(const void* g, void* l) {
    __builtin_amdgcn_global_load_lds(
        (const __attribute__((address_space(1))) unsigned int*)g,
        (__attribute__((address_space(3))) unsigned int*)l, 16, 0, 0);
}

// Pre-transpose weights into bf16 B-fragment-friendly [n][k] layouts in d_ws.
// Wa rows 32..63 are pre-scaled by log2e so the kernel can use exp2 directly.
__global__ __launch_bounds__(256) void prep_kernel(
    const float* __restrict__ Wc, const float* __restrict__ Wf,
    const float* __restrict__ Wa, unsigned short* __restrict__ ws)
{
    int t = blockIdx.x * blockDim.x + threadIdx.x;
    int stride = gridDim.x * blockDim.x;
    for (int i = t; i < 32 * 64; i += stride) {
        int n = i >> 6, k = i & 63;
        ws[WS_WC + n * XS_STRIDE + k] = f2bf(Wc[k * ECD + n]);
    }
    for (int i = t; i < 128 * 64; i += stride) {
        int n = i >> 6, k = i & 63;
        ws[WS_WF + n * XS_STRIDE + k] = f2bf(Wf[k * LATD + n]);
    }
    for (int i = t; i < 128 * 32; i += stride) {
        int n = i >> 5, k = i & 31;
        ws[WS_WA + n * WA_STRIDE + k] = f2bf(Wa[(ECD + k) * LATD + n] * 1.44269504f);
    }
}

// FINAL (r14 revert): best verified configuration after the full 16-round
// exploration. 2 elements interleaved per block (512 blocks, 2 blocks/CU),
// streaming gload_lds ingestion with both-sides XOR swizzle (bit-exact,
// r12/r13-verified), per-g weights register-hoisted, dynamic s-loop,
// double-buffered xstage with counted vmcnt(4).
// Matrix of falsified alternatives: occupancy 1-8 waves/SIMD (r1/r3/r9/r16),
// weight source L2==LDS==regs (r7/r8/r10/r14), 4-elem ILP (r9, spills),
// reg-staged contiguous loads (r11/r12, spills), high-TLP x streaming
// (r16, clean, neutral). Residual ~40us arm_main is invariant with all
// pipes <20% busy — structural at HIP source level for this harness.
// Key algebra (verified): self_rep/mean_rep/ba constant along n -> cancel
// in softmax(axis=n); att = softmax_n(enc_comm @ Wa[32:64]); local_data /
// Wa[0:32] / Wa[64:96] / ba never touch the output.
__global__ __launch_bounds__(256, 2) void arm_main(
    const float* __restrict__ xg,   // neighbor [B][256][64]
    const float* __restrict__ bcv,  // bc [32]
    const float* __restrict__ bfv,  // bf [128]
    const float* __restrict__ wl,   // Wl [128][128]
    const float* __restrict__ blv,  // bl [128]
    const unsigned short* __restrict__ ws,
    float* __restrict__ out)        // [B][128]
{
    __shared__ float xstage[4][2][1024];               // 32768 B [wave][buf][16x256B]
    __shared__ unsigned short ecst[4][16 * EC_STRIDE]; // 5120 B per-wave ec tile
    __shared__ float aggnum[2][4][LATD];               // 4096 B
    __shared__ float aggden[2][4][LATD];               // 4096 B
    __shared__ float aggfull[2][LATD];                 // 1024 B
    __shared__ float wlpart[2][2][LATD];               // 2048 B
    // total 49152 B -> 2 blocks/CU

    const int b0   = blockIdx.x;          // gridDim.x == 512
    const int b1   = blockIdx.x + 512;
    const int tid  = threadIdx.x;
    const int lane = tid & 63;
    const int w    = tid >> 6;   // wave id, owns rows 64w..64w+63 per element
    const int l15  = lane & 15;
    const int q    = lane >> 4;

    // ---- hoist ALL weights/biases into registers, issued FIRST so the
    // counted vmcnt below (which also covers them) is exact, and their
    // ~300cy L2 latency hides under the staging prologue. 112+18 VGPR.
    bf16x8 wf0g[8], wf1g[8], wagg[8];
    float  bfl8[8];
    #pragma unroll
    for (int g = 0; g < 8; ++g) {
        const int r0 = g * 16 + l15;
        wf0g[g] = *reinterpret_cast<const bf16x8*>(&ws[WS_WF + r0 * XS_STRIDE + q * 8]);
        wf1g[g] = *reinterpret_cast<const bf16x8*>(&ws[WS_WF + r0 * XS_STRIDE + 32 + q * 8]);
        wagg[g] = *reinterpret_cast<const bf16x8*>(&ws[WS_WA + r0 * WA_STRIDE + q * 8]);
        bfl8[g] = bfv[r0];
    }
    bf16x8 wfrag[2][2];
    #pragma unroll
    for (int ks = 0; ks < 2; ++ks)
        #pragma unroll
        for (int nb = 0; nb < 2; ++nb)
            wfrag[ks][nb] = *reinterpret_cast<const bf16x8*>(
                &ws[WS_WC + (nb * 16 + l15) * XS_STRIDE + ks * 32 + q * 8]);
    float bc0 = bcv[l15], bc1 = bcv[16 + l15];

    // ---- staging: tile s (0..7): elem = s>>2, 16-row chunk = s&3 (4KB).
    // Linear LDS off Li = i*1024 + lane*16; row = i*4 + q (tile-local).
    // Global src = Li ^ ((row&7)<<4)  (involution; verified bit-exact r12/r13).
    const float* xw0 = xg + (size_t)b0 * NB * DIN + w * 64 * DIN;
    const float* xw1 = xg + (size_t)b1 * NB * DIN + w * 64 * DIN;

#define STAGE(s_)                                                             \
    {                                                                         \
        const char* tb = (const char*)(((s_) < 4 ? xw0 : xw1) + ((s_) & 3) * 1024); \
        float* lb = &xstage[w][(s_) & 1][0];                                  \
        _Pragma("unroll")                                                     \
        for (int i = 0; i < 4; ++i) {                                         \
            unsigned off = (unsigned)(i * 1024 + lane * 16);                  \
            unsigned r7  = (unsigned)((i * 4 + q) & 7);                       \
            gload_lds16(tb + (off ^ (r7 << 4)), lb + i * 256);                \
        }                                                                     \
    }

    // prologue: prime tiles 0 (buf0) and 1 (buf1)
    STAGE(0);
    STAGE(1);

    float num[8] = {0.f, 0.f, 0.f, 0.f, 0.f, 0.f, 0.f, 0.f};
    float den[8] = {0.f, 0.f, 0.f, 0.f, 0.f, 0.f, 0.f, 0.f};

    // frag read offsets (swizzled): o0 = (l15*256 + q*32) ^ ((l15&7)<<4);
    // +16/+128/+144 toggles live in untouched bits -> XOR composition exact.
    const unsigned o0 = ((unsigned)(l15 * 256 + q * 32)) ^ ((unsigned)(l15 & 7) << 4);

    #pragma unroll 1
    for (int s = 0; s < 8; ++s) {
        // (1) tile s resident: everything except tile s+1's 4 loads done
        //     (weight loads precede STAGE(0) in the in-order vmem queue,
        //     so vmcnt(4) also guarantees the register weights are live).
        if (s < 7) { asm volatile("s_waitcnt vmcnt(4)" ::: "memory"); }
        else       { asm volatile("s_waitcnt vmcnt(0)" ::: "memory"); }

        // (2) fragment reads (4 x ds_read_b128, conflict-free via swizzle)
        const char* xb = (const char*)&xstage[w][s & 1][0];
        float4 r0 = *reinterpret_cast<const float4*>(xb + o0);
        float4 r1 = *reinterpret_cast<const float4*>(xb + (o0 ^ 16));
        float4 r2 = *reinterpret_cast<const float4*>(xb + (o0 ^ 128));
        float4 r3 = *reinterpret_cast<const float4*>(xb + (o0 ^ 144));

        // (3) reads retired -> safe to overwrite this buffer with tile s+2;
        //     issued BEFORE compute so ~2 compute phases cover its latency.
        asm volatile("s_waitcnt lgkmcnt(0)" ::: "memory");
        if (s + 2 < 8) { STAGE(s + 2); }

        bf16x8 xf0 = pack8(r0, r1);
        bf16x8 xf1 = pack8(r2, r3);

        // (4) enc_comm tile: relu(X*Wc + bc) -> ec tile (wave-private LDS;
        // same-wave DS ordering, no barrier). Bias folded into acc init.
        f32x4 a0 = {bc0, bc0, bc0, bc0};
        f32x4 a1 = {bc1, bc1, bc1, bc1};
        a0 = MFMA(xf0, wfrag[0][0], a0); a0 = MFMA(xf1, wfrag[1][0], a0);
        a1 = MFMA(xf0, wfrag[0][1], a1); a1 = MFMA(xf1, wfrag[1][1], a1);
        #pragma unroll
        for (int r = 0; r < 4; ++r) {
            int row = q * 4 + r;   // C/D: row = quad*4 + reg (tile-local)
            unsigned pk = cvt2(fmaxf(a0[r], 0.f), fmaxf(a1[r], 0.f));
            ecst[w][row * EC_STRIDE + l15]      = (unsigned short)pk;
            ecst[w][row * EC_STRIDE + 16 + l15] = (unsigned short)(pk >> 16);
        }
        bf16x8 ecf = *reinterpret_cast<const bf16x8*>(&ecst[w][l15 * EC_STRIDE + q * 8]);

        // (5) all 8 g for this tile: PURE register math (weights hoisted) —
        // no loads of any kind inside this loop.
        #pragma unroll
        for (int g = 0; g < 8; ++g) {
            f32x4 z = {bfl8[g], bfl8[g], bfl8[g], bfl8[g]};  // bf in acc init
            z = MFMA(xf0, wf0g[g], z);
            f32x4 ef = MFMA(xf1, wf1g[g], z);
            f32x4 zz = {0.f, 0.f, 0.f, 0.f};                 // ba cancels
            f32x4 lg = MFMA(ecf, wagg[g], zz);
            #pragma unroll
            for (int r = 0; r < 4; ++r) {
                float ev = fmaxf(ef[r], 0.f);
                float p  = fexp2(lg[r]);    // Wa pre-scaled by log2e in prep
                num[g] = fmaf(p, ev, num[g]);
                den[g] += p;
            }
        }

        // (6) element boundary: reduce across lanes, store partials, reset
        if ((s & 3) == 3) {
            const int e = s >> 2;
            #pragma unroll
            for (int g = 0; g < 8; ++g) {
                float n2 = num[g], d2 = den[g];
                n2 += __shfl_xor(n2, 16, 64); n2 += __shfl_xor(n2, 32, 64);
                d2 += __shfl_xor(d2, 16, 64); d2 += __shfl_xor(d2, 32, 64);
                if (lane < 16) {
                    aggnum[e][w][g * 16 + lane] = n2;
                    aggden[e][w][g * 16 + lane] = d2;
                }
                num[g] = 0.f;
                den[g] = 0.f;
            }
        }
    }
#undef STAGE
    __syncthreads();

    // ---- combine wave partials (both halves of the block active) ----
    {
        int e = tid >> 7, c = tid & 127;
        float n2 = aggnum[e][0][c] + aggnum[e][1][c] + aggnum[e][2][c] + aggnum[e][3][c];
        float d2 = aggden[e][0][c] + aggden[e][1][c] + aggden[e][2][c] + aggden[e][3][c];
        aggfull[e][c] = n2 / d2;
    }
    __syncthreads();

    // ---- out = relu(agg @ Wl + bl): wl loaded ONCE, used for both elems ----
    {
        int c = tid & 127, h = tid >> 7;
        float acc0 = 0.f, acc1 = 0.f;
        #pragma unroll 16
        for (int k = h * 64; k < h * 64 + 64; ++k) {
            float wv = wl[k * LATD + c];
            acc0 = fmaf(aggfull[0][k], wv, acc0);
            acc1 = fmaf(aggfull[1][k], wv, acc1);
        }
        wlpart[h][0][c] = acc0;
        wlpart[h][1][c] = acc1;
    }
    __syncthreads();
    {
        int e = tid >> 7, c = tid & 127;
        out[(size_t)(e ? b1 : b0) * LATD + c] =
            fmaxf(wlpart[0][e][c] + wlpart[1][e][c] + blv[c], 0.f);
    }
}

extern "C" void kernel_launch(void* const* d_in, const int* in_sizes, int n_in,
                              void* d_out, int out_size, void* d_ws, size_t ws_size,
                              hipStream_t stream)
{
    const float* xg  = (const float*)d_in[1];
    const float* wc  = (const float*)d_in[2];
    const float* bc_ = (const float*)d_in[3];
    const float* wf  = (const float*)d_in[4];
    const float* bf_ = (const float*)d_in[5];
    const float* wa  = (const float*)d_in[6];
    const float* wl  = (const float*)d_in[8];
    const float* bl_ = (const float*)d_in[9];
    unsigned short* wsp = (unsigned short*)d_ws;   // needs 33,280 B of ws
    float* out = (float*)d_out;

    prep_kernel<<<8, 256, 0, stream>>>(wc, wf, wa, wsp);
    arm_main<<<512, 256, 0, stream>>>(xg, bc_, bf_, wl, bl_, wsp, out);
}